// Round 16
// baseline (373.000 us; speedup 1.0000x reference)
//
#include <hip/hip_runtime.h>
#include <hip/hip_bf16.h>

#define NODES 13627
#define DIM   500

typedef short short8 __attribute__((ext_vector_type(8)));
typedef float f32x4 __attribute__((ext_vector_type(4)));
typedef float floatx2 __attribute__((ext_vector_type(2)));

__device__ inline float wave_reduce_sum(float v) {
#pragma unroll
    for (int o = 32; o > 0; o >>= 1) v += __shfl_xor(v, o, 64);
    return v;
}

__device__ inline void store_v(float* p, float v) { *p = v; }
__device__ inline void store_v(__hip_bfloat16* p, float v) { *p = __float2bfloat16(v); }

// bf16 (packed pair in uint) -> f32, exact
__device__ inline float blo(unsigned w) { unsigned t = w << 16;        return __builtin_bit_cast(float, t); }
__device__ inline float bhi(unsigned w) { unsigned t = w & 0xffff0000u; return __builtin_bit_cast(float, t); }

// fp8 e4m3 (OCP, HW convert)
__device__ inline unsigned char to_fp8(float v) {
    int r = __builtin_amdgcn_cvt_pk_fp8_f32(v, v, 0, false);
    return (unsigned char)(r & 0xff);
}

// pack two floats into bf16x2 word (RNE)
__device__ inline unsigned pk2bf(float a, float b) {
    unsigned la = (unsigned)__builtin_bit_cast(unsigned short, __float2bfloat16(a));
    unsigned hb = (unsigned)__builtin_bit_cast(unsigned short, __float2bfloat16(b));
    return la | (hb << 16);
}

// ---- DPP 16-lane sum step: pure VALU (no ds_swizzle / lgkmcnt wait).
template <int CTRL>
__device__ inline float dpp_add_step(float v) {
    int s = __builtin_amdgcn_update_dpp(0, __builtin_bit_cast(int, v), CTRL, 0xf, 0xf, true);
    return v + __builtin_bit_cast(float, s);
}
__device__ inline float quad16_reduce(float v) {
    v = dpp_add_step<0x128>(v);   // row_ror:8
    v = dpp_add_step<0x124>(v);   // row_ror:4
    v = dpp_add_step<0x4E>(v);    // quad_perm [2,3,0,1]  (xor 2)
    v = dpp_add_step<0xB1>(v);    // quad_perm [1,0,3,2]  (xor 1)
    return v;
}

struct b4 { __hip_bfloat16 a, b, c, d; };

// ---------------------------------------------------------------------------
// CSR scan + scatter (hist fused into convert_all)
// ---------------------------------------------------------------------------
__global__ __launch_bounds__(1024) void scan_kernel(int* __restrict__ cnt_cur,
                                                    int* __restrict__ off, int n) {
    __shared__ int wsum[16];
    const int tid = threadIdx.x, lane = tid & 63, w = tid >> 6;
    int carry = 0;
    for (int base = 0; base < n; base += 1024) {
        int i = base + tid;
        int v = (i < n) ? cnt_cur[i] : 0;
        int s = v;
#pragma unroll
        for (int o = 1; o < 64; o <<= 1) {
            int t = __shfl_up(s, o, 64);
            if (lane >= o) s += t;
        }
        if (lane == 63) wsum[w] = s;
        __syncthreads();
        if (w == 0 && lane < 16) {
            int x = wsum[lane];
            int sx = x;
#pragma unroll
            for (int o = 1; o < 16; o <<= 1) {
                int t = __shfl_up(sx, o, 64);
                if (lane >= o) sx += t;
            }
            wsum[lane] = sx;
        }
        __syncthreads();
        int wo = (w == 0) ? 0 : wsum[w - 1];
        int total = wsum[15];
        int excl = carry + wo + (s - v);
        if (i < n) { off[i] = excl; cnt_cur[i] = excl; }
        carry += total;
        __syncthreads();
    }
    if (tid == 0) off[n] = carry;
}

__global__ __launch_bounds__(256) void scatter_kernel(const int* __restrict__ src,
                                                      const int* __restrict__ dst,
                                                      int* __restrict__ cur,
                                                      int* __restrict__ ssrc, int E) {
    int i = blockIdx.x * blockDim.x + threadIdx.x;
    if (i < E) {
        int p = atomicAdd(&cur[dst[i]], 1);
        ssrc[p] = src[i];
    }
}

// ---------------------------------------------------------------------------
// Fused conversion / packing + degree histogram.
// WcT = concat(W1T rows 0..639, WsT rows 0..255) for the fused GEMM.
// ---------------------------------------------------------------------------
__global__ __launch_bounds__(256) void convert_all_kernel(
    const float* __restrict__ x,
    const float* __restrict__ Wl1, const float* __restrict__ Wr1,
    const float* __restrict__ Wl2, const float* __restrict__ Wr2,
    const float* __restrict__ Ws1, const float* __restrict__ Ws2,
    const float* __restrict__ bs1, const float* __restrict__ bs2,
    __hip_bfloat16* __restrict__ WcT, __hip_bfloat16* __restrict__ W2T,
    float* __restrict__ bcat, __hip_bfloat16* __restrict__ xb,
    const int* __restrict__ dst, int* __restrict__ cnt, int E, int M) {
    int i = blockIdx.x * 256 + threadIdx.x;
    if (i < E) atomicAdd(&cnt[dst[i]], 1);   // fused degree histogram
    if (i < 327680) {
        int n = i >> 9, k = i & 511;
        float v = 0.f;
        if (k < 500) {
            if (n < 300) v = Wl1[k * 300 + n];
            else if (n < 600) v = Wr1[k * 300 + n - 300];
        }
        WcT[i] = __float2bfloat16(v);        // rows 0..639
    } else if (i < 409600) {
        int j = i - 327680;
        int n = j / 320, k = j - n * 320;
        float v = 0.f;
        if (k < 300) {
            if (n < 100) v = Wl2[k * 100 + n];
            else if (n < 200) v = Wr2[k * 100 + n - 100];
        }
        W2T[j] = __float2bfloat16(v);
    } else if (i < 540672) {
        int j = i - 409600;                  // [0, 131072) = 256x512
        int n = j >> 9, k = j & 511;
        float v = 0.f;
        if (k < 500) {
            if (n < 100) v = Ws1[k * 100 + n];
            else if (n < 200) v = Ws2[k * 100 + n - 100];
        }
        WcT[327680 + j] = __float2bfloat16(v);   // rows 640..895
    } else if (i < 540928) {
        int n = i - 540672;
        float v = 0.f;
        if (n < 100) v = bs1[n];
        else if (n < 200) v = bs2[n - 100];
        bcat[n] = v;
    } else {
        int j = i - 540928;
        if (j >= M * 128) return;
        int m = j >> 7, k = (j & 127) << 2;
        b4 o;
        if (k < 500) {
            float4 v = *(const float4*)(x + (size_t)m * 500 + k);
            o.a = __float2bfloat16(v.x); o.b = __float2bfloat16(v.y);
            o.c = __float2bfloat16(v.z); o.d = __float2bfloat16(v.w);
        } else {
            o.a = o.b = o.c = o.d = __float2bfloat16(0.f);
        }
        *(b4*)(xb + (size_t)m * 512 + k) = o;
    }
}

// ---------------------------------------------------------------------------
// bf16 MFMA GEMM: C[M,Nn] = A[M,Kp] @ BT[Nn,Kp]^T   (BM=128, BN=64, BK=32)
// R26 XCD-chunk swizzle (FETCH 58->12MB, verified). R28:
//  (a) LDS rotation swizzle pos(c,sl)=c*16+((sl+4c)&15) on store AND read —
//      old layout was a 4-way write bank conflict (6.9M conflict cycles).
//  (b) register prefetch: tile k+1's global loads issue after barrier 1 and
//      are consumed a full MFMA phase later (hides ~200-300cy L2 latency
//      that was exposed every K-step at 2.5 blocks/CU).
// ---------------------------------------------------------------------------
template <int EPI, typename TC>
__global__ __launch_bounds__(256) void mfma_gemm(
    const __hip_bfloat16* __restrict__ A, const __hip_bfloat16* __restrict__ BT,
    TC* __restrict__ C, const float* __restrict__ bias, const float* __restrict__ h2,
    unsigned char* __restrict__ p8, __hip_bfloat16* __restrict__ pb,
    int M, int Kp, int Nn, int ldc) {
    __shared__ short AsF[8 * 64 * 8];
    __shared__ short BsF[4 * 64 * 8];
    const int t = threadIdx.x;
    const int w = t >> 6, lane = t & 63;
    const int c = t & 3, rr = t >> 2;

    // ---- XCD-chunk swizzle (bijective for any nwg, m204 formula) ----
    const int nwg = gridDim.x * gridDim.y;
    int id = blockIdx.y * gridDim.x + blockIdx.x;
    {
        const int xcd = id & 7, idx = id >> 3;
        const int qq = nwg >> 3, r8 = nwg & 7;
        id = (xcd < r8 ? xcd * (qq + 1) : r8 * (qq + 1) + (xcd - r8) * qq) + idx;
    }
    const int m0 = (id / gridDim.x) * 128, n0 = (id % gridDim.x) * 64;

    // ---- LDS positions: store side (per-thread) and read side (per-lane) ----
    const int slw = rr & 15;                         // row within 16-chunk
    const int miw = rr >> 4;                         // chunk sub-index 0..3
    const int posw = c * 16 + ((slw + 4 * c) & 15);  // rotation swizzle
    const int kc = lane >> 4, rl = lane & 15;
    const int posr = kc * 16 + ((rl + 4 * kc) & 15);

    // per-lane global rows (invariant over k)
    int gmA[2];
#pragma unroll
    for (int r = 0; r < 2; r++) {
        int gm = m0 + r * 64 + rr;
        gmA[r] = (gm >= M) ? (M - 1) : gm;
    }
    const int gnB = n0 + rr;

    f32x4 acc[2][4];
#pragma unroll
    for (int i = 0; i < 2; i++)
#pragma unroll
        for (int j = 0; j < 4; j++) acc[i][j] = (f32x4){0.f, 0.f, 0.f, 0.f};

    // ---- prologue: load tile k0=0 into registers ----
    float4 ra[2], rbv;
#pragma unroll
    for (int r = 0; r < 2; r++)
        ra[r] = *(const float4*)(A + (size_t)gmA[r] * Kp + c * 8);
    rbv = *(const float4*)(BT + (size_t)gnB * Kp + c * 8);

    for (int k0 = 0; k0 < Kp; k0 += 32) {
        // ---- store current tile to LDS (swizzled) ----
#pragma unroll
        for (int r = 0; r < 2; r++)
            *(float4*)(&AsF[((r * 4 + miw) * 64 + posw) * 8]) = ra[r];
        *(float4*)(&BsF[(miw * 64 + posw) * 8]) = rbv;
        __syncthreads();
        // ---- prefetch next tile (consumed after next barrier) ----
        if (k0 + 32 < Kp) {
#pragma unroll
            for (int r = 0; r < 2; r++)
                ra[r] = *(const float4*)(A + (size_t)gmA[r] * Kp + k0 + 32 + c * 8);
            rbv = *(const float4*)(BT + (size_t)gnB * Kp + k0 + 32 + c * 8);
        }
        // ---- compute ----
        short8 a0 = *(const short8*)(&AsF[((w * 2 + 0) * 64 + posr) * 8]);
        short8 a1 = *(const short8*)(&AsF[((w * 2 + 1) * 64 + posr) * 8]);
#pragma unroll
        for (int j = 0; j < 4; j++) {
            short8 b = *(const short8*)(&BsF[(j * 64 + posr) * 8]);
            acc[0][j] = __builtin_amdgcn_mfma_f32_16x16x32_bf16(a0, b, acc[0][j], 0, 0, 0);
            acc[1][j] = __builtin_amdgcn_mfma_f32_16x16x32_bf16(a1, b, acc[1][j], 0, 0, 0);
        }
        __syncthreads();
    }

    const int q = lane >> 4, sl = lane & 15;
#pragma unroll
    for (int i = 0; i < 2; i++) {
#pragma unroll
        for (int j = 0; j < 4; j++) {
#pragma unroll
            for (int reg = 0; reg < 4; reg++) {
                int gm = m0 + w * 32 + i * 16 + q * 4 + reg;
                int gn = n0 + j * 16 + sl;
                if (gm >= M) continue;
                float v = acc[i][j][reg];
                if constexpr (EPI == 1) {
                    if (gn < 300)       p8[(size_t)gm * 304 + gn] = to_fp8(v);
                    else if (gn < 600)  pb[(size_t)gm * 320 + (gn - 300)] = __float2bfloat16(v);
                    else if (gn < 620)  pb[(size_t)gm * 320 + (gn - 300)] = __float2bfloat16(0.f);
                    else if (gn < 624)  p8[(size_t)gm * 304 + (gn - 320)] = 0;
                    else if (gn >= 640 && gn < 840) {
                        int cn = gn - 640;
                        ((float*)C)[(size_t)gm * 200 + cn] = fmaxf(v + bias[cn], 0.f);
                    }
                } else if constexpr (EPI == 2) {
                    if (gn < 100)       p8[(size_t)gm * 112 + gn] = to_fp8(v);
                    else if (gn < 200)  pb[(size_t)gm * 128 + (gn - 100)] = __float2bfloat16(v);
                    else if (gn < 212)  p8[(size_t)gm * 112 + (gn - 100)] = 0;
                    else if (gn < 240)  pb[(size_t)gm * 128 + (gn - 112)] = __float2bfloat16(0.f);
                } else {
                    store_v(&C[(size_t)gm * ldc + gn], v);
                }
            }
        }
    }
}

// ---------------------------------------------------------------------------
// GATv2 edge+aggregate on fp8 xl table (L2-resident) + bf16 xr.
// R22 structure. FUSE=true (gat2) folds skip_add + gemm_vec1 into epilogue.
// ---------------------------------------------------------------------------
template <int F, int NJ, int SL8, int SRB, int SOUT, int JSL, typename TOUT, bool FUSE>
__global__ __launch_bounds__(64, 4) void gat_f8_kernel(
    const unsigned char* __restrict__ xl8, const __hip_bfloat16* __restrict__ xrb,
    const float* __restrict__ att, const float* __restrict__ bias,
    const int* __restrict__ off, const int* __restrict__ ssrc,
    TOUT* __restrict__ out,
    const float* __restrict__ wpre, unsigned char* __restrict__ z8o,
    float* __restrict__ xl3, float* __restrict__ xr3,
    const float* __restrict__ wl3, const float* __restrict__ wr3, int n) {
    const int lane = threadIdx.x;
    const int sl = lane & 15, q = lane >> 4;
    const int wid = blockIdx.x;          // grid.x == n exactly

    floatx2 attv[NJ * 2], xrv[NJ * 2], acc[NJ * 2];
    const unsigned* xru = (const unsigned*)xrb + (size_t)wid * (SRB / 2);
#pragma unroll
    for (int j = 0; j < NJ; j++) {
        const int f0 = sl * 4 + j * 64;
        if (f0 < F) {
            float4 a4 = *(const float4*)(att + f0);
            attv[j * 2 + 0] = (floatx2){a4.x, a4.y};
            attv[j * 2 + 1] = (floatx2){a4.z, a4.w};
        } else {
            attv[j * 2 + 0] = (floatx2){0.f, 0.f};
            attv[j * 2 + 1] = (floatx2){0.f, 0.f};
        }
        unsigned u0 = __builtin_nontemporal_load(xru + (f0 >> 1));
        unsigned u1 = __builtin_nontemporal_load(xru + (f0 >> 1) + 1);
        xrv[j * 2 + 0] = (floatx2){blo(u0), bhi(u0)};
        xrv[j * 2 + 1] = (floatx2){blo(u1), bhi(u1)};
        acc[j * 2 + 0] = (floatx2){0.f, 0.f};
        acc[j * 2 + 1] = (floatx2){0.f, 0.f};
    }

    const int s0 = off[wid], s1 = off[wid + 1];
    const int eb = s0 - 1;              // self loop lives at slot s0-1
    const int ee = s1;
    float den = 0.f;
    const int myoff = sl * 4;

    // ---- pipeline prologue: indices for iter 0 and 1, rows for iter 0 ----
    int srcB;
    unsigned u[NJ];
    {
        int eq0 = eb + q;
        int srcA = wid;
        if (eq0 >= s0 && eq0 < ee) srcA = __builtin_nontemporal_load(ssrc + eq0);
        int eq1 = eb + 4 + q;
        srcB = wid;
        if (eq1 >= s0 && eq1 < ee) srcB = __builtin_nontemporal_load(ssrc + eq1);
        const unsigned char* row = xl8 + (size_t)srcA * SL8;
#pragma unroll
        for (int j = 0; j < NJ; j++) {
            const bool ld = (j < NJ - 1) || (sl < JSL);
            u[j] = ld ? *(const unsigned*)(row + myoff + j * 64) : 0u;
        }
    }

    // ---- deferred-softmax pending state (nothing pending yet: gate = 0) ----
    float p_pend = 0.f, gate = 0.f;
    unsigned u_pend[NJ];
#pragma unroll
    for (int j = 0; j < NJ; j++) u_pend[j] = 0u;

    for (int e0 = eb; e0 < ee; e0 += 4) {
        // ---- issue index load for iteration i+2 ----
        int srcC = wid;
        {
            int eq2 = e0 + 8 + q;
            if (eq2 >= s0 && eq2 < ee) srcC = __builtin_nontemporal_load(ssrc + eq2);
        }
        // ---- issue row loads for iteration i+1 (index already resident) ----
        unsigned un[NJ];
        {
            const unsigned char* row1 = xl8 + (size_t)srcB * SL8;
#pragma unroll
            for (int j = 0; j < NJ; j++) {
                const bool ld = (j < NJ - 1) || (sl < JSL);
                un[j] = ld ? *(const unsigned*)(row1 + myoff + j * 64) : 0u;
            }
        }
        // ---- finish PENDING quad: DPP reduce -> exp -> re-decode -> acc ----
        {
            float pp = quad16_reduce(p_pend);
            float ex = gate * __expf(pp);
            den += ex;
            floatx2 ex2 = (floatx2){ex, ex};
#pragma unroll
            for (int j = 0; j < NJ; j++) {
                floatx2 lo = __builtin_amdgcn_cvt_pk_f32_fp8((int)u_pend[j], false);
                floatx2 hi = __builtin_amdgcn_cvt_pk_f32_fp8((int)u_pend[j], true);
                acc[j * 2 + 0] += ex2 * lo;
                acc[j * 2 + 1] += ex2 * hi;
            }
        }
        // ---- CURRENT quad score (packed f32x2) -> becomes pending ----
        {
            floatx2 p2 = (floatx2){0.f, 0.f};
#pragma unroll
            for (int j = 0; j < NJ; j++) {
                floatx2 lo = __builtin_amdgcn_cvt_pk_f32_fp8((int)u[j], false);
                floatx2 hi = __builtin_amdgcn_cvt_pk_f32_fp8((int)u[j], true);
                floatx2 s0v = lo + xrv[j * 2 + 0];
                floatx2 s1v = hi + xrv[j * 2 + 1];
                floatx2 g0 = __builtin_elementwise_max(s0v, 0.2f * s0v);
                floatx2 g1 = __builtin_elementwise_max(s1v, 0.2f * s1v);
                p2 += attv[j * 2 + 0] * g0;
                p2 += attv[j * 2 + 1] * g1;
            }
            p_pend = p2.x + p2.y;
            gate = ((e0 + q) < ee) ? 1.f : 0.f;
        }
        // ---- rotate pipeline (u -> u_pend, un -> u) ----
#pragma unroll
        for (int j = 0; j < NJ; j++) { u_pend[j] = u[j]; u[j] = un[j]; }
        srcB = srcC;
    }
    // ---- drain the final pending quad ----
    {
        float pp = quad16_reduce(p_pend);
        float ex = gate * __expf(pp);
        den += ex;
        floatx2 ex2 = (floatx2){ex, ex};
#pragma unroll
        for (int j = 0; j < NJ; j++) {
            floatx2 lo = __builtin_amdgcn_cvt_pk_f32_fp8((int)u_pend[j], false);
            floatx2 hi = __builtin_amdgcn_cvt_pk_f32_fp8((int)u_pend[j], true);
            acc[j * 2 + 0] += ex2 * lo;
            acc[j * 2 + 1] += ex2 * hi;
        }
    }

    // cross-quad butterfly (crosses 16-lane rows, DPP can't — keep shfl)
    float* af = (float*)acc;
#pragma unroll
    for (int o = 16; o <= 32; o <<= 1) {
        den += __shfl_xor(den, o, 64);
#pragma unroll
        for (int i = 0; i < NJ * 4; i++) af[i] += __shfl_xor(af[i], o, 64);
    }

    if (q == 0) {
        const float inv = 1.f / (den + 1e-16f);
        if constexpr (FUSE) {
            // fused: h2 in-register -> z8 + layer-3 projections (row-local)
            float pl = 0.f, pr = 0.f;
#pragma unroll
            for (int j = 0; j < NJ; j++) {
                const int f0 = sl * 4 + j * 64;
#pragma unroll
                for (int cc = 0; cc < 4; cc++) {
                    const int f = f0 + cc;
                    if (f < F) {
                        float h2v = fmaxf(af[j * 4 + cc] * inv + bias[f], 0.f);
                        float preA = wpre[(size_t)wid * 200 + f];
                        float preB = wpre[(size_t)wid * 200 + 100 + f];
                        float xov = preA + h2v;
                        z8o[(size_t)wid * 128 + f] = to_fp8(preB + h2v);
                        pl += xov * wl3[f];
                        pr += xov * wr3[f];
                    } else {
                        z8o[(size_t)wid * 128 + f] = 0;
                    }
                }
            }
            pl = quad16_reduce(pl);
            pr = quad16_reduce(pr);
            if (sl == 0) { xl3[wid] = pl; xr3[wid] = pr; }
        } else {
#pragma unroll
            for (int j = 0; j < NJ; j++) {
                const int f0 = sl * 4 + j * 64;
                if (f0 >= SOUT) continue;
                float r[4];
#pragma unroll
                for (int cc = 0; cc < 4; cc++) {
                    const int f = f0 + cc;
                    float v = 0.f;
                    if (f < F) v = fmaxf(af[j * 4 + cc] * inv + bias[f], 0.f);
                    r[cc] = v;
                }
                if constexpr (sizeof(TOUT) == 4) {   // float out
                    *(float4*)((float*)out + (size_t)wid * SOUT + f0) =
                        make_float4(r[0], r[1], r[2], r[3]);
                } else {                             // bf16 out
                    unsigned* op = (unsigned*)out + (size_t)wid * (SOUT / 2) + (f0 >> 1);
                    op[0] = pk2bf(r[0], r[1]);
                    op[1] = pk2bf(r[2], r[3]);
                }
            }
        }
    }
}

// ---------------------------------------------------------------------------
// Layer-3 GAT (F=1): wave per node + finalize folded into the LAST block.
// ---------------------------------------------------------------------------
__global__ __launch_bounds__(256) void gat3_kernel(
    const float* __restrict__ xl3, const float* __restrict__ xr3,
    const float* __restrict__ att3, const float* __restrict__ b3,
    const int* __restrict__ off, const int* __restrict__ ssrc,
    float* __restrict__ out, int n,
    const float* __restrict__ part, int nb,
    const float* __restrict__ c1, const float* __restrict__ c2, int E) {
    __shared__ float sp[4], sn[4];
    if (blockIdx.x == gridDim.x - 1) {
        const int tid = threadIdx.x, lane = tid & 63, w = tid >> 6;
        float p = 0.f, q2 = 0.f;
        for (int i = tid; i < nb; i += 256) { p += part[i]; q2 += part[nb + i]; }
        p = wave_reduce_sum(p);
        q2 = wave_reduce_sum(q2);
        if (lane == 0) { sp[w] = p; sn[w] = q2; }
        __syncthreads();
        if (tid == 0) {
            float tp = sp[0] + sp[1] + sp[2] + sp[3];
            float tq = sn[0] + sn[1] + sn[2] + sn[3];
            out[n]     = -(tp + tq) / (float)E;
            out[n + 1] = c1[0];
            out[n + 2] = c2[0];
        }
        return;
    }
    const int wid = blockIdx.x * 4 + (threadIdx.x >> 6);
    const int lane = threadIdx.x & 63;
    if (wid >= n) return;
    const float xrv = xr3[wid];
    const float att = att3[0];
    float num = 0.f, den = 0.f;
    const int s0 = off[wid], s1 = off[wid + 1];
    for (int e = s0 - 1 + lane; e < s1; e += 64) {
        int src = (e < s0) ? wid : ssrc[e];
        float xlv = xl3[src];
        float t = xlv + xrv;
        float g = t > 0.f ? t : 0.2f * t;
        float ex = __expf(g * att);
        den += ex;
        num += ex * xlv;
    }
    num = wave_reduce_sum(num);
    den = wave_reduce_sum(den);
    if (lane == 0) out[wid] = num / (den + 1e-16f) + b3[0];
}

// ---------------------------------------------------------------------------
// Link-prediction loss on fp8 z [N,128]. 16-lane/edge coalesced + DPP reduce.
// ---------------------------------------------------------------------------
__global__ __launch_bounds__(256) void loss_kernel(
    const unsigned char* __restrict__ z8, const int* __restrict__ pos,
    const int* __restrict__ neg, float* __restrict__ part, int nb, int E) {
    const int lane = threadIdx.x & 63;
    const int sl = lane & 15;
    const int wlocal = threadIdx.x >> 6;
    const int q = lane >> 4;
    const int nq = gridDim.x * 16;
    const int qid = (blockIdx.x * 4 + wlocal) * 4 + q;
    const int total = 2 * E;
    float psum = 0.f, nsum = 0.f;

    for (int base = qid; base < total; base += 4 * nq) {
        uint2 au[4], bu[4];
        bool act[4], isN[4];
#pragma unroll
        for (int s = 0; s < 4; s++) {
            int it = base + s * nq;
            act[s] = it < total;
            int itc = act[s] ? it : 0;
            isN[s] = itc >= E;
            int e = isN[s] ? itc - E : itc;
            const int* ei = isN[s] ? neg : pos;
            int u = ei[e], v = ei[E + e];
            au[s] = *(const uint2*)(z8 + (size_t)u * 128 + sl * 8);
            bu[s] = *(const uint2*)(z8 + (size_t)v * 128 + sl * 8);
        }
#pragma unroll
        for (int s = 0; s < 4; s++) {
            floatx2 a0 = __builtin_amdgcn_cvt_pk_f32_fp8((int)au[s].x, false);
            floatx2 a1 = __builtin_amdgcn_cvt_pk_f32_fp8((int)au[s].x, true);
            floatx2 a2 = __builtin_amdgcn_cvt_pk_f32_fp8((int)au[s].y, false);
            floatx2 a3 = __builtin_amdgcn_cvt_pk_f32_fp8((int)au[s].y, true);
            floatx2 b0 = __builtin_amdgcn_cvt_pk_f32_fp8((int)bu[s].x, false);
            floatx2 b1 = __builtin_amdgcn_cvt_pk_f32_fp8((int)bu[s].x, true);
            floatx2 b2 = __builtin_amdgcn_cvt_pk_f32_fp8((int)bu[s].y, false);
            floatx2 b3 = __builtin_amdgcn_cvt_pk_f32_fp8((int)bu[s].y, true);
            float p = a0.x * b0.x + a0.y * b0.y + a1.x * b1.x + a1.y * b1.y
                    + a2.x * b2.x + a2.y * b2.y + a3.x * b3.x + a3.y * b3.y;
            p = quad16_reduce(p);
            if (sl == 0 && act[s]) {
                float sig = __builtin_amdgcn_rcpf(1.f + __expf(-p));
                if (isN[s]) nsum += __logf(1.f - sig + 1e-15f);
                else        psum += __logf(sig + 1e-15f);
            }
        }
    }
    float pw = wave_reduce_sum(psum);
    float nw = wave_reduce_sum(nsum);
    __shared__ float sp[4], sn[4];
    if (lane == 0) { sp[wlocal] = pw; sn[wlocal] = nw; }
    __syncthreads();
    if (threadIdx.x == 0) {
        part[blockIdx.x]      = sp[0] + sp[1] + sp[2] + sp[3];
        part[nb + blockIdx.x] = sn[0] + sn[1] + sn[2] + sn[3];
    }
}

// ---------------------------------------------------------------------------
extern "C" void kernel_launch(void* const* d_in, const int* in_sizes, int n_in,
                              void* d_out, int out_size, void* d_ws, size_t ws_size,
                              hipStream_t stream) {
    const float* x      = (const float*)d_in[0];
    const int*   ei     = (const int*)d_in[1];
    const int*   nei    = (const int*)d_in[2];
    const float* Wl1    = (const float*)d_in[3];
    const float* Wr1    = (const float*)d_in[4];
    const float* att1   = (const float*)d_in[5];
    const float* b1     = (const float*)d_in[6];
    const float* Wl2    = (const float*)d_in[7];
    const float* Wr2    = (const float*)d_in[8];
    const float* att2   = (const float*)d_in[9];
    const float* b2     = (const float*)d_in[10];
    const float* Wl3    = (const float*)d_in[11];
    const float* Wr3    = (const float*)d_in[12];
    const float* att3   = (const float*)d_in[13];
    const float* b3     = (const float*)d_in[14];
    const float* Wlin1  = (const float*)d_in[15];
    const float* blin1  = (const float*)d_in[16];
    const float* Wlin2  = (const float*)d_in[17];
    const float* blin2  = (const float*)d_in[18];
    const float* c1     = (const float*)d_in[19];
    const float* c2     = (const float*)d_in[20];
    float* out = (float*)d_out;

    const int E = in_sizes[1] / 2;   // 504378
    const int N = NODES;
    const int LOSS_BLOCKS = 4096;

    // ---- workspace carve (bytes); ws_size = 256MB, we use ~50MB ----
    char* ws = (char*)d_ws;
    unsigned char*  xl8  = (unsigned char*)(ws + 0);          // [N,304] fp8
    unsigned char*  xl28 = (unsigned char*)(ws + 0);          // [N,112] fp8 (after gat1)
    __hip_bfloat16* xrb  = (__hip_bfloat16*)(ws + 4194304);   // [N,320] bf16
    __hip_bfloat16* xr2b = (__hip_bfloat16*)(ws + 4194304);   // [N,128] bf16 (after gat1)
    unsigned char*  z8   = (unsigned char*)(ws + 9645312);    // [N,128] fp8
    __hip_bfloat16* h1b  = (__hip_bfloat16*)(ws + 12915712);  // [N,320] bf16 (gat1 -> L2 GEMM)
    __hip_bfloat16* xb   = (__hip_bfloat16*)(ws + 21637120);  // [N,512] bf16
    __hip_bfloat16* WcT  = (__hip_bfloat16*)(ws + 35591168);  // [896,512] (W1|Ws)
    __hip_bfloat16* W2T  = (__hip_bfloat16*)(ws + 36508672);  // [256,320]
    float*          bcat = (float*)(ws + 36672512);           // [256]
    float*          xl3  = (float*)(ws + 36673536);
    float*          xr3  = (float*)(ws + 36728064);
    int*            ioff = (int*)(ws + 36782592);             // N+1
    int*            cur  = (int*)(ws + 36837376);             // N
    int*            ssrc = (int*)(ws + 36892160);             // E
    float*          part = (float*)(ws + 38909952);           // [2*LOSS_BLOCKS]
    float*          wpre = (float*)(ws + 39000064);           // [N,200] f32 skip-pre

    hipMemsetAsync(cur, 0, sizeof(int) * N, stream);

    // ---- pack inputs/weights + degree histogram (one fused launch) ----
    convert_all_kernel<<<(540928 + N * 128 + 255) / 256, 256, 0, stream>>>(
        x, Wl1, Wr1, Wl2, Wr2, Wlin1, Wlin2, blin1, blin2,
        WcT, W2T, bcat, xb, ei + E, cur, E, N);

    // ---- CSR: scan + scatter ----
    scan_kernel<<<1, 1024, 0, stream>>>(cur, ioff, N);
    scatter_kernel<<<(E + 255) / 256, 256, 0, stream>>>(ei, ei + E, cur, ssrc, E);

    // ---- layer 1 GEMM fused with skip GEMM: xl8 + xrb + wpre ----
    mfma_gemm<1, float><<<dim3(14, 107), 256, 0, stream>>>(
        xb, WcT, wpre, bcat, nullptr, xl8, xrb, N, 512, 896, 200);
    gat_f8_kernel<300, 5, 304, 320, 320, 11, __hip_bfloat16, false>
        <<<N, 64, 0, stream>>>(xl8, xrb, att1, b1, ioff, ssrc, h1b,
                               nullptr, nullptr, nullptr, nullptr, nullptr, nullptr, N);

    // ---- layer 2: GEMM -> xl28 fp8 [N,112] + xr2b bf16 [N,128] ----
    mfma_gemm<2, __hip_bfloat16><<<dim3(4, 107), 256, 0, stream>>>(
        h1b, W2T, (__hip_bfloat16*)nullptr, nullptr, nullptr, xl28, xr2b, N, 320, 256, 0);
    // ---- gat2 FUSED: h2 in-register -> z8 + xl3/xr3 (skip_add + gemm_vec1) ----
    gat_f8_kernel<100, 2, 112, 128, 100, 9, float, true>
        <<<N, 64, 0, stream>>>(xl28, xr2b, att2, b2, ioff, ssrc, (float*)nullptr,
                               wpre, z8, xl3, xr3, Wl3, Wr3, N);

    // ---- reconstruction loss ----
    loss_kernel<<<LOSS_BLOCKS, 256, 0, stream>>>(z8, ei, nei, part, LOSS_BLOCKS, E);

    // ---- layer 3 + finalize (last block) ----
    gat3_kernel<<<(N + 3) / 4 + 1, 256, 0, stream>>>(
        xl3, xr3, att3, b3, ioff, ssrc, out, N, part, LOSS_BLOCKS, c1, c2, E);
}

// Round 17
// 332.345 us; speedup vs baseline: 1.1223x; 1.1223x over previous
//
#include <hip/hip_runtime.h>
#include <hip/hip_bf16.h>

#define NODES 13627
#define DIM   500

typedef short short8 __attribute__((ext_vector_type(8)));
typedef float f32x4 __attribute__((ext_vector_type(4)));
typedef float floatx2 __attribute__((ext_vector_type(2)));

__device__ inline float wave_reduce_sum(float v) {
#pragma unroll
    for (int o = 32; o > 0; o >>= 1) v += __shfl_xor(v, o, 64);
    return v;
}

__device__ inline void store_v(float* p, float v) { *p = v; }
__device__ inline void store_v(__hip_bfloat16* p, float v) { *p = __float2bfloat16(v); }

// bf16 (packed pair in uint) -> f32, exact
__device__ inline float blo(unsigned w) { unsigned t = w << 16;        return __builtin_bit_cast(float, t); }
__device__ inline float bhi(unsigned w) { unsigned t = w & 0xffff0000u; return __builtin_bit_cast(float, t); }

// fp8 e4m3 (OCP, HW convert)
__device__ inline unsigned char to_fp8(float v) {
    int r = __builtin_amdgcn_cvt_pk_fp8_f32(v, v, 0, false);
    return (unsigned char)(r & 0xff);
}

// pack two floats into bf16x2 word (RNE)
__device__ inline unsigned pk2bf(float a, float b) {
    unsigned la = (unsigned)__builtin_bit_cast(unsigned short, __float2bfloat16(a));
    unsigned hb = (unsigned)__builtin_bit_cast(unsigned short, __float2bfloat16(b));
    return la | (hb << 16);
}

// ---- DPP 16-lane sum step: pure VALU (no ds_swizzle / lgkmcnt wait).
template <int CTRL>
__device__ inline float dpp_add_step(float v) {
    int s = __builtin_amdgcn_update_dpp(0, __builtin_bit_cast(int, v), CTRL, 0xf, 0xf, true);
    return v + __builtin_bit_cast(float, s);
}
__device__ inline float quad16_reduce(float v) {
    v = dpp_add_step<0x128>(v);   // row_ror:8
    v = dpp_add_step<0x124>(v);   // row_ror:4
    v = dpp_add_step<0x4E>(v);    // quad_perm [2,3,0,1]  (xor 2)
    v = dpp_add_step<0xB1>(v);    // quad_perm [1,0,3,2]  (xor 1)
    return v;
}

struct b4 { __hip_bfloat16 a, b, c, d; };

// ---------------------------------------------------------------------------
// CSR scan + scatter (hist fused into convert_all)
// ---------------------------------------------------------------------------
__global__ __launch_bounds__(1024) void scan_kernel(int* __restrict__ cnt_cur,
                                                    int* __restrict__ off, int n) {
    __shared__ int wsum[16];
    const int tid = threadIdx.x, lane = tid & 63, w = tid >> 6;
    int carry = 0;
    for (int base = 0; base < n; base += 1024) {
        int i = base + tid;
        int v = (i < n) ? cnt_cur[i] : 0;
        int s = v;
#pragma unroll
        for (int o = 1; o < 64; o <<= 1) {
            int t = __shfl_up(s, o, 64);
            if (lane >= o) s += t;
        }
        if (lane == 63) wsum[w] = s;
        __syncthreads();
        if (w == 0 && lane < 16) {
            int x = wsum[lane];
            int sx = x;
#pragma unroll
            for (int o = 1; o < 16; o <<= 1) {
                int t = __shfl_up(sx, o, 64);
                if (lane >= o) sx += t;
            }
            wsum[lane] = sx;
        }
        __syncthreads();
        int wo = (w == 0) ? 0 : wsum[w - 1];
        int total = wsum[15];
        int excl = carry + wo + (s - v);
        if (i < n) { off[i] = excl; cnt_cur[i] = excl; }
        carry += total;
        __syncthreads();
    }
    if (tid == 0) off[n] = carry;
}

__global__ __launch_bounds__(256) void scatter_kernel(const int* __restrict__ src,
                                                      const int* __restrict__ dst,
                                                      int* __restrict__ cur,
                                                      int* __restrict__ ssrc, int E) {
    int i = blockIdx.x * blockDim.x + threadIdx.x;
    if (i < E) {
        int p = atomicAdd(&cur[dst[i]], 1);
        ssrc[p] = src[i];
    }
}

// ---------------------------------------------------------------------------
// Fused conversion / packing + degree histogram.
// WcT = concat(W1T rows 0..639, WsT rows 0..255) for the fused GEMM.
// ---------------------------------------------------------------------------
__global__ __launch_bounds__(256) void convert_all_kernel(
    const float* __restrict__ x,
    const float* __restrict__ Wl1, const float* __restrict__ Wr1,
    const float* __restrict__ Wl2, const float* __restrict__ Wr2,
    const float* __restrict__ Ws1, const float* __restrict__ Ws2,
    const float* __restrict__ bs1, const float* __restrict__ bs2,
    __hip_bfloat16* __restrict__ WcT, __hip_bfloat16* __restrict__ W2T,
    float* __restrict__ bcat, __hip_bfloat16* __restrict__ xb,
    const int* __restrict__ dst, int* __restrict__ cnt, int E, int M) {
    int i = blockIdx.x * 256 + threadIdx.x;
    if (i < E) atomicAdd(&cnt[dst[i]], 1);   // fused degree histogram
    if (i < 327680) {
        int n = i >> 9, k = i & 511;
        float v = 0.f;
        if (k < 500) {
            if (n < 300) v = Wl1[k * 300 + n];
            else if (n < 600) v = Wr1[k * 300 + n - 300];
        }
        WcT[i] = __float2bfloat16(v);        // rows 0..639
    } else if (i < 409600) {
        int j = i - 327680;
        int n = j / 320, k = j - n * 320;
        float v = 0.f;
        if (k < 300) {
            if (n < 100) v = Wl2[k * 100 + n];
            else if (n < 200) v = Wr2[k * 100 + n - 100];
        }
        W2T[j] = __float2bfloat16(v);
    } else if (i < 540672) {
        int j = i - 409600;                  // [0, 131072) = 256x512
        int n = j >> 9, k = j & 511;
        float v = 0.f;
        if (k < 500) {
            if (n < 100) v = Ws1[k * 100 + n];
            else if (n < 200) v = Ws2[k * 100 + n - 100];
        }
        WcT[327680 + j] = __float2bfloat16(v);   // rows 640..895
    } else if (i < 540928) {
        int n = i - 540672;
        float v = 0.f;
        if (n < 100) v = bs1[n];
        else if (n < 200) v = bs2[n - 100];
        bcat[n] = v;
    } else {
        int j = i - 540928;
        if (j >= M * 128) return;
        int m = j >> 7, k = (j & 127) << 2;
        b4 o;
        if (k < 500) {
            float4 v = *(const float4*)(x + (size_t)m * 500 + k);
            o.a = __float2bfloat16(v.x); o.b = __float2bfloat16(v.y);
            o.c = __float2bfloat16(v.z); o.d = __float2bfloat16(v.w);
        } else {
            o.a = o.b = o.c = o.d = __float2bfloat16(0.f);
        }
        *(b4*)(xb + (size_t)m * 512 + k) = o;
    }
}

// ---------------------------------------------------------------------------
// bf16 MFMA GEMM: C[M,Nn] = A[M,Kp] @ BT[Nn,Kp]^T   (BM=128, BN=64, BK=64)
// R29: R15 layout restored (R16's swizzle+prefetch regressed; conflict count
// proved layout-invariant — inherent b128 multi-cycle, not fixable), with
// BK=64: two 32-k halves per iteration -> 6 loads in flight (vs 3), HALF
// the iterations and barrier pairs (8 vs 16 at K=512; 5 vs 10 at K=320).
// Kp must be a multiple of 64 (512, 320 ✓). XCD-chunk swizzle kept
// (FETCH 58->12MB verified). Same fragments, same accumulation order.
// ---------------------------------------------------------------------------
template <int EPI, typename TC>
__global__ __launch_bounds__(256) void mfma_gemm(
    const __hip_bfloat16* __restrict__ A, const __hip_bfloat16* __restrict__ BT,
    TC* __restrict__ C, const float* __restrict__ bias, const float* __restrict__ h2,
    unsigned char* __restrict__ p8, __hip_bfloat16* __restrict__ pb,
    int M, int Kp, int Nn, int ldc) {
    __shared__ short AsF[2][8 * 64 * 8];
    __shared__ short BsF[2][4 * 64 * 8];
    const int t = threadIdx.x;
    const int w = t >> 6, lane = t & 63;
    const int c = t & 3, rr = t >> 2;

    // ---- XCD-chunk swizzle (bijective for any nwg, m204 formula) ----
    const int nwg = gridDim.x * gridDim.y;
    int id = blockIdx.y * gridDim.x + blockIdx.x;
    {
        const int xcd = id & 7, idx = id >> 3;
        const int qq = nwg >> 3, r8 = nwg & 7;
        id = (xcd < r8 ? xcd * (qq + 1) : r8 * (qq + 1) + (xcd - r8) * qq) + idx;
    }
    const int m0 = (id / gridDim.x) * 128, n0 = (id % gridDim.x) * 64;

    f32x4 acc[2][4];
#pragma unroll
    for (int i = 0; i < 2; i++)
#pragma unroll
        for (int j = 0; j < 4; j++) acc[i][j] = (f32x4){0.f, 0.f, 0.f, 0.f};

    for (int k0 = 0; k0 < Kp; k0 += 64) {
        // ---- stage both 32-k halves (6 loads in flight) ----
#pragma unroll
        for (int h = 0; h < 2; h++) {
#pragma unroll
            for (int r = 0; r < 2; r++) {
                int m = r * 64 + rr;
                int gm = m0 + m; if (gm >= M) gm = M - 1;
                float4 v = *(const float4*)(A + (size_t)gm * Kp + k0 + h * 32 + c * 8);
                int mi = m >> 4, sl = m & 15;
                *(float4*)(&AsF[h][(mi * 64 + c * 16 + sl) * 8]) = v;
            }
            {
                int n = rr;
                float4 v = *(const float4*)(BT + (size_t)(n0 + n) * Kp + k0 + h * 32 + c * 8);
                int ni = n >> 4, sl = n & 15;
                *(float4*)(&BsF[h][(ni * 64 + c * 16 + sl) * 8]) = v;
            }
        }
        __syncthreads();
#pragma unroll
        for (int h = 0; h < 2; h++) {
            short8 a0 = *(const short8*)(&AsF[h][((w * 2 + 0) * 64 + lane) * 8]);
            short8 a1 = *(const short8*)(&AsF[h][((w * 2 + 1) * 64 + lane) * 8]);
#pragma unroll
            for (int j = 0; j < 4; j++) {
                short8 b = *(const short8*)(&BsF[h][(j * 64 + lane) * 8]);
                acc[0][j] = __builtin_amdgcn_mfma_f32_16x16x32_bf16(a0, b, acc[0][j], 0, 0, 0);
                acc[1][j] = __builtin_amdgcn_mfma_f32_16x16x32_bf16(a1, b, acc[1][j], 0, 0, 0);
            }
        }
        __syncthreads();
    }

    const int q = lane >> 4, sl = lane & 15;
#pragma unroll
    for (int i = 0; i < 2; i++) {
#pragma unroll
        for (int j = 0; j < 4; j++) {
#pragma unroll
            for (int reg = 0; reg < 4; reg++) {
                int gm = m0 + w * 32 + i * 16 + q * 4 + reg;
                int gn = n0 + j * 16 + sl;
                if (gm >= M) continue;
                float v = acc[i][j][reg];
                if constexpr (EPI == 1) {
                    if (gn < 300)       p8[(size_t)gm * 304 + gn] = to_fp8(v);
                    else if (gn < 600)  pb[(size_t)gm * 320 + (gn - 300)] = __float2bfloat16(v);
                    else if (gn < 620)  pb[(size_t)gm * 320 + (gn - 300)] = __float2bfloat16(0.f);
                    else if (gn < 624)  p8[(size_t)gm * 304 + (gn - 320)] = 0;
                    else if (gn >= 640 && gn < 840) {
                        int cn = gn - 640;
                        ((float*)C)[(size_t)gm * 200 + cn] = fmaxf(v + bias[cn], 0.f);
                    }
                } else if constexpr (EPI == 2) {
                    if (gn < 100)       p8[(size_t)gm * 112 + gn] = to_fp8(v);
                    else if (gn < 200)  pb[(size_t)gm * 128 + (gn - 100)] = __float2bfloat16(v);
                    else if (gn < 212)  p8[(size_t)gm * 112 + (gn - 100)] = 0;
                    else if (gn < 240)  pb[(size_t)gm * 128 + (gn - 112)] = __float2bfloat16(0.f);
                } else {
                    store_v(&C[(size_t)gm * ldc + gn], v);
                }
            }
        }
    }
}

// ---------------------------------------------------------------------------
// GATv2 edge+aggregate on fp8 xl table (L2-resident) + bf16 xr.
// R22 structure. FUSE=true (gat2) folds skip_add + gemm_vec1 into epilogue.
// ---------------------------------------------------------------------------
template <int F, int NJ, int SL8, int SRB, int SOUT, int JSL, typename TOUT, bool FUSE>
__global__ __launch_bounds__(64, 4) void gat_f8_kernel(
    const unsigned char* __restrict__ xl8, const __hip_bfloat16* __restrict__ xrb,
    const float* __restrict__ att, const float* __restrict__ bias,
    const int* __restrict__ off, const int* __restrict__ ssrc,
    TOUT* __restrict__ out,
    const float* __restrict__ wpre, unsigned char* __restrict__ z8o,
    float* __restrict__ xl3, float* __restrict__ xr3,
    const float* __restrict__ wl3, const float* __restrict__ wr3, int n) {
    const int lane = threadIdx.x;
    const int sl = lane & 15, q = lane >> 4;
    const int wid = blockIdx.x;          // grid.x == n exactly

    floatx2 attv[NJ * 2], xrv[NJ * 2], acc[NJ * 2];
    const unsigned* xru = (const unsigned*)xrb + (size_t)wid * (SRB / 2);
#pragma unroll
    for (int j = 0; j < NJ; j++) {
        const int f0 = sl * 4 + j * 64;
        if (f0 < F) {
            float4 a4 = *(const float4*)(att + f0);
            attv[j * 2 + 0] = (floatx2){a4.x, a4.y};
            attv[j * 2 + 1] = (floatx2){a4.z, a4.w};
        } else {
            attv[j * 2 + 0] = (floatx2){0.f, 0.f};
            attv[j * 2 + 1] = (floatx2){0.f, 0.f};
        }
        unsigned u0 = __builtin_nontemporal_load(xru + (f0 >> 1));
        unsigned u1 = __builtin_nontemporal_load(xru + (f0 >> 1) + 1);
        xrv[j * 2 + 0] = (floatx2){blo(u0), bhi(u0)};
        xrv[j * 2 + 1] = (floatx2){blo(u1), bhi(u1)};
        acc[j * 2 + 0] = (floatx2){0.f, 0.f};
        acc[j * 2 + 1] = (floatx2){0.f, 0.f};
    }

    const int s0 = off[wid], s1 = off[wid + 1];
    const int eb = s0 - 1;              // self loop lives at slot s0-1
    const int ee = s1;
    float den = 0.f;
    const int myoff = sl * 4;

    // ---- pipeline prologue: indices for iter 0 and 1, rows for iter 0 ----
    int srcB;
    unsigned u[NJ];
    {
        int eq0 = eb + q;
        int srcA = wid;
        if (eq0 >= s0 && eq0 < ee) srcA = __builtin_nontemporal_load(ssrc + eq0);
        int eq1 = eb + 4 + q;
        srcB = wid;
        if (eq1 >= s0 && eq1 < ee) srcB = __builtin_nontemporal_load(ssrc + eq1);
        const unsigned char* row = xl8 + (size_t)srcA * SL8;
#pragma unroll
        for (int j = 0; j < NJ; j++) {
            const bool ld = (j < NJ - 1) || (sl < JSL);
            u[j] = ld ? *(const unsigned*)(row + myoff + j * 64) : 0u;
        }
    }

    // ---- deferred-softmax pending state (nothing pending yet: gate = 0) ----
    float p_pend = 0.f, gate = 0.f;
    unsigned u_pend[NJ];
#pragma unroll
    for (int j = 0; j < NJ; j++) u_pend[j] = 0u;

    for (int e0 = eb; e0 < ee; e0 += 4) {
        // ---- issue index load for iteration i+2 ----
        int srcC = wid;
        {
            int eq2 = e0 + 8 + q;
            if (eq2 >= s0 && eq2 < ee) srcC = __builtin_nontemporal_load(ssrc + eq2);
        }
        // ---- issue row loads for iteration i+1 (index already resident) ----
        unsigned un[NJ];
        {
            const unsigned char* row1 = xl8 + (size_t)srcB * SL8;
#pragma unroll
            for (int j = 0; j < NJ; j++) {
                const bool ld = (j < NJ - 1) || (sl < JSL);
                un[j] = ld ? *(const unsigned*)(row1 + myoff + j * 64) : 0u;
            }
        }
        // ---- finish PENDING quad: DPP reduce -> exp -> re-decode -> acc ----
        {
            float pp = quad16_reduce(p_pend);
            float ex = gate * __expf(pp);
            den += ex;
            floatx2 ex2 = (floatx2){ex, ex};
#pragma unroll
            for (int j = 0; j < NJ; j++) {
                floatx2 lo = __builtin_amdgcn_cvt_pk_f32_fp8((int)u_pend[j], false);
                floatx2 hi = __builtin_amdgcn_cvt_pk_f32_fp8((int)u_pend[j], true);
                acc[j * 2 + 0] += ex2 * lo;
                acc[j * 2 + 1] += ex2 * hi;
            }
        }
        // ---- CURRENT quad score (packed f32x2) -> becomes pending ----
        {
            floatx2 p2 = (floatx2){0.f, 0.f};
#pragma unroll
            for (int j = 0; j < NJ; j++) {
                floatx2 lo = __builtin_amdgcn_cvt_pk_f32_fp8((int)u[j], false);
                floatx2 hi = __builtin_amdgcn_cvt_pk_f32_fp8((int)u[j], true);
                floatx2 s0v = lo + xrv[j * 2 + 0];
                floatx2 s1v = hi + xrv[j * 2 + 1];
                floatx2 g0 = __builtin_elementwise_max(s0v, 0.2f * s0v);
                floatx2 g1 = __builtin_elementwise_max(s1v, 0.2f * s1v);
                p2 += attv[j * 2 + 0] * g0;
                p2 += attv[j * 2 + 1] * g1;
            }
            p_pend = p2.x + p2.y;
            gate = ((e0 + q) < ee) ? 1.f : 0.f;
        }
        // ---- rotate pipeline (u -> u_pend, un -> u) ----
#pragma unroll
        for (int j = 0; j < NJ; j++) { u_pend[j] = u[j]; u[j] = un[j]; }
        srcB = srcC;
    }
    // ---- drain the final pending quad ----
    {
        float pp = quad16_reduce(p_pend);
        float ex = gate * __expf(pp);
        den += ex;
        floatx2 ex2 = (floatx2){ex, ex};
#pragma unroll
        for (int j = 0; j < NJ; j++) {
            floatx2 lo = __builtin_amdgcn_cvt_pk_f32_fp8((int)u_pend[j], false);
            floatx2 hi = __builtin_amdgcn_cvt_pk_f32_fp8((int)u_pend[j], true);
            acc[j * 2 + 0] += ex2 * lo;
            acc[j * 2 + 1] += ex2 * hi;
        }
    }

    // cross-quad butterfly (crosses 16-lane rows, DPP can't — keep shfl)
    float* af = (float*)acc;
#pragma unroll
    for (int o = 16; o <= 32; o <<= 1) {
        den += __shfl_xor(den, o, 64);
#pragma unroll
        for (int i = 0; i < NJ * 4; i++) af[i] += __shfl_xor(af[i], o, 64);
    }

    if (q == 0) {
        const float inv = 1.f / (den + 1e-16f);
        if constexpr (FUSE) {
            // fused: h2 in-register -> z8 + layer-3 projections (row-local)
            float pl = 0.f, pr = 0.f;
#pragma unroll
            for (int j = 0; j < NJ; j++) {
                const int f0 = sl * 4 + j * 64;
#pragma unroll
                for (int cc = 0; cc < 4; cc++) {
                    const int f = f0 + cc;
                    if (f < F) {
                        float h2v = fmaxf(af[j * 4 + cc] * inv + bias[f], 0.f);
                        float preA = wpre[(size_t)wid * 200 + f];
                        float preB = wpre[(size_t)wid * 200 + 100 + f];
                        float xov = preA + h2v;
                        z8o[(size_t)wid * 128 + f] = to_fp8(preB + h2v);
                        pl += xov * wl3[f];
                        pr += xov * wr3[f];
                    } else {
                        z8o[(size_t)wid * 128 + f] = 0;
                    }
                }
            }
            pl = quad16_reduce(pl);
            pr = quad16_reduce(pr);
            if (sl == 0) { xl3[wid] = pl; xr3[wid] = pr; }
        } else {
#pragma unroll
            for (int j = 0; j < NJ; j++) {
                const int f0 = sl * 4 + j * 64;
                if (f0 >= SOUT) continue;
                float r[4];
#pragma unroll
                for (int cc = 0; cc < 4; cc++) {
                    const int f = f0 + cc;
                    float v = 0.f;
                    if (f < F) v = fmaxf(af[j * 4 + cc] * inv + bias[f], 0.f);
                    r[cc] = v;
                }
                if constexpr (sizeof(TOUT) == 4) {   // float out
                    *(float4*)((float*)out + (size_t)wid * SOUT + f0) =
                        make_float4(r[0], r[1], r[2], r[3]);
                } else {                             // bf16 out
                    unsigned* op = (unsigned*)out + (size_t)wid * (SOUT / 2) + (f0 >> 1);
                    op[0] = pk2bf(r[0], r[1]);
                    op[1] = pk2bf(r[2], r[3]);
                }
            }
        }
    }
}

// ---------------------------------------------------------------------------
// Layer-3 GAT (F=1): wave per node + finalize folded into the LAST block.
// ---------------------------------------------------------------------------
__global__ __launch_bounds__(256) void gat3_kernel(
    const float* __restrict__ xl3, const float* __restrict__ xr3,
    const float* __restrict__ att3, const float* __restrict__ b3,
    const int* __restrict__ off, const int* __restrict__ ssrc,
    float* __restrict__ out, int n,
    const float* __restrict__ part, int nb,
    const float* __restrict__ c1, const float* __restrict__ c2, int E) {
    __shared__ float sp[4], sn[4];
    if (blockIdx.x == gridDim.x - 1) {
        const int tid = threadIdx.x, lane = tid & 63, w = tid >> 6;
        float p = 0.f, q2 = 0.f;
        for (int i = tid; i < nb; i += 256) { p += part[i]; q2 += part[nb + i]; }
        p = wave_reduce_sum(p);
        q2 = wave_reduce_sum(q2);
        if (lane == 0) { sp[w] = p; sn[w] = q2; }
        __syncthreads();
        if (tid == 0) {
            float tp = sp[0] + sp[1] + sp[2] + sp[3];
            float tq = sn[0] + sn[1] + sn[2] + sn[3];
            out[n]     = -(tp + tq) / (float)E;
            out[n + 1] = c1[0];
            out[n + 2] = c2[0];
        }
        return;
    }
    const int wid = blockIdx.x * 4 + (threadIdx.x >> 6);
    const int lane = threadIdx.x & 63;
    if (wid >= n) return;
    const float xrv = xr3[wid];
    const float att = att3[0];
    float num = 0.f, den = 0.f;
    const int s0 = off[wid], s1 = off[wid + 1];
    for (int e = s0 - 1 + lane; e < s1; e += 64) {
        int src = (e < s0) ? wid : ssrc[e];
        float xlv = xl3[src];
        float t = xlv + xrv;
        float g = t > 0.f ? t : 0.2f * t;
        float ex = __expf(g * att);
        den += ex;
        num += ex * xlv;
    }
    num = wave_reduce_sum(num);
    den = wave_reduce_sum(den);
    if (lane == 0) out[wid] = num / (den + 1e-16f) + b3[0];
}

// ---------------------------------------------------------------------------
// Link-prediction loss on fp8 z [N,128]. 16-lane/edge coalesced + DPP reduce.
// ---------------------------------------------------------------------------
__global__ __launch_bounds__(256) void loss_kernel(
    const unsigned char* __restrict__ z8, const int* __restrict__ pos,
    const int* __restrict__ neg, float* __restrict__ part, int nb, int E) {
    const int lane = threadIdx.x & 63;
    const int sl = lane & 15;
    const int wlocal = threadIdx.x >> 6;
    const int q = lane >> 4;
    const int nq = gridDim.x * 16;
    const int qid = (blockIdx.x * 4 + wlocal) * 4 + q;
    const int total = 2 * E;
    float psum = 0.f, nsum = 0.f;

    for (int base = qid; base < total; base += 4 * nq) {
        uint2 au[4], bu[4];
        bool act[4], isN[4];
#pragma unroll
        for (int s = 0; s < 4; s++) {
            int it = base + s * nq;
            act[s] = it < total;
            int itc = act[s] ? it : 0;
            isN[s] = itc >= E;
            int e = isN[s] ? itc - E : itc;
            const int* ei = isN[s] ? neg : pos;
            int u = ei[e], v = ei[E + e];
            au[s] = *(const uint2*)(z8 + (size_t)u * 128 + sl * 8);
            bu[s] = *(const uint2*)(z8 + (size_t)v * 128 + sl * 8);
        }
#pragma unroll
        for (int s = 0; s < 4; s++) {
            floatx2 a0 = __builtin_amdgcn_cvt_pk_f32_fp8((int)au[s].x, false);
            floatx2 a1 = __builtin_amdgcn_cvt_pk_f32_fp8((int)au[s].x, true);
            floatx2 a2 = __builtin_amdgcn_cvt_pk_f32_fp8((int)au[s].y, false);
            floatx2 a3 = __builtin_amdgcn_cvt_pk_f32_fp8((int)au[s].y, true);
            floatx2 b0 = __builtin_amdgcn_cvt_pk_f32_fp8((int)bu[s].x, false);
            floatx2 b1 = __builtin_amdgcn_cvt_pk_f32_fp8((int)bu[s].x, true);
            floatx2 b2 = __builtin_amdgcn_cvt_pk_f32_fp8((int)bu[s].y, false);
            floatx2 b3 = __builtin_amdgcn_cvt_pk_f32_fp8((int)bu[s].y, true);
            float p = a0.x * b0.x + a0.y * b0.y + a1.x * b1.x + a1.y * b1.y
                    + a2.x * b2.x + a2.y * b2.y + a3.x * b3.x + a3.y * b3.y;
            p = quad16_reduce(p);
            if (sl == 0 && act[s]) {
                float sig = __builtin_amdgcn_rcpf(1.f + __expf(-p));
                if (isN[s]) nsum += __logf(1.f - sig + 1e-15f);
                else        psum += __logf(sig + 1e-15f);
            }
        }
    }
    float pw = wave_reduce_sum(psum);
    float nw = wave_reduce_sum(nsum);
    __shared__ float sp[4], sn[4];
    if (lane == 0) { sp[wlocal] = pw; sn[wlocal] = nw; }
    __syncthreads();
    if (threadIdx.x == 0) {
        part[blockIdx.x]      = sp[0] + sp[1] + sp[2] + sp[3];
        part[nb + blockIdx.x] = sn[0] + sn[1] + sn[2] + sn[3];
    }
}

// ---------------------------------------------------------------------------
extern "C" void kernel_launch(void* const* d_in, const int* in_sizes, int n_in,
                              void* d_out, int out_size, void* d_ws, size_t ws_size,
                              hipStream_t stream) {
    const float* x      = (const float*)d_in[0];
    const int*   ei     = (const int*)d_in[1];
    const int*   nei    = (const int*)d_in[2];
    const float* Wl1    = (const float*)d_in[3];
    const float* Wr1    = (const float*)d_in[4];
    const float* att1   = (const float*)d_in[5];
    const float* b1     = (const float*)d_in[6];
    const float* Wl2    = (const float*)d_in[7];
    const float* Wr2    = (const float*)d_in[8];
    const float* att2   = (const float*)d_in[9];
    const float* b2     = (const float*)d_in[10];
    const float* Wl3    = (const float*)d_in[11];
    const float* Wr3    = (const float*)d_in[12];
    const float* att3   = (const float*)d_in[13];
    const float* b3     = (const float*)d_in[14];
    const float* Wlin1  = (const float*)d_in[15];
    const float* blin1  = (const float*)d_in[16];
    const float* Wlin2  = (const float*)d_in[17];
    const float* blin2  = (const float*)d_in[18];
    const float* c1     = (const float*)d_in[19];
    const float* c2     = (const float*)d_in[20];
    float* out = (float*)d_out;

    const int E = in_sizes[1] / 2;   // 504378
    const int N = NODES;
    const int LOSS_BLOCKS = 4096;

    // ---- workspace carve (bytes); ws_size = 256MB, we use ~50MB ----
    char* ws = (char*)d_ws;
    unsigned char*  xl8  = (unsigned char*)(ws + 0);          // [N,304] fp8
    unsigned char*  xl28 = (unsigned char*)(ws + 0);          // [N,112] fp8 (after gat1)
    __hip_bfloat16* xrb  = (__hip_bfloat16*)(ws + 4194304);   // [N,320] bf16
    __hip_bfloat16* xr2b = (__hip_bfloat16*)(ws + 4194304);   // [N,128] bf16 (after gat1)
    unsigned char*  z8   = (unsigned char*)(ws + 9645312);    // [N,128] fp8
    __hip_bfloat16* h1b  = (__hip_bfloat16*)(ws + 12915712);  // [N,320] bf16 (gat1 -> L2 GEMM)
    __hip_bfloat16* xb   = (__hip_bfloat16*)(ws + 21637120);  // [N,512] bf16
    __hip_bfloat16* WcT  = (__hip_bfloat16*)(ws + 35591168);  // [896,512] (W1|Ws)
    __hip_bfloat16* W2T  = (__hip_bfloat16*)(ws + 36508672);  // [256,320]
    float*          bcat = (float*)(ws + 36672512);           // [256]
    float*          xl3  = (float*)(ws + 36673536);
    float*          xr3  = (float*)(ws + 36728064);
    int*            ioff = (int*)(ws + 36782592);             // N+1
    int*            cur  = (int*)(ws + 36837376);             // N
    int*            ssrc = (int*)(ws + 36892160);             // E
    float*          part = (float*)(ws + 38909952);           // [2*LOSS_BLOCKS]
    float*          wpre = (float*)(ws + 39000064);           // [N,200] f32 skip-pre

    hipMemsetAsync(cur, 0, sizeof(int) * N, stream);

    // ---- pack inputs/weights + degree histogram (one fused launch) ----
    convert_all_kernel<<<(540928 + N * 128 + 255) / 256, 256, 0, stream>>>(
        x, Wl1, Wr1, Wl2, Wr2, Wlin1, Wlin2, blin1, blin2,
        WcT, W2T, bcat, xb, ei + E, cur, E, N);

    // ---- CSR: scan + scatter ----
    scan_kernel<<<1, 1024, 0, stream>>>(cur, ioff, N);
    scatter_kernel<<<(E + 255) / 256, 256, 0, stream>>>(ei, ei + E, cur, ssrc, E);

    // ---- layer 1 GEMM fused with skip GEMM: xl8 + xrb + wpre ----
    mfma_gemm<1, float><<<dim3(14, 107), 256, 0, stream>>>(
        xb, WcT, wpre, bcat, nullptr, xl8, xrb, N, 512, 896, 200);
    gat_f8_kernel<300, 5, 304, 320, 320, 11, __hip_bfloat16, false>
        <<<N, 64, 0, stream>>>(xl8, xrb, att1, b1, ioff, ssrc, h1b,
                               nullptr, nullptr, nullptr, nullptr, nullptr, nullptr, N);

    // ---- layer 2: GEMM -> xl28 fp8 [N,112] + xr2b bf16 [N,128] ----
    mfma_gemm<2, __hip_bfloat16><<<dim3(4, 107), 256, 0, stream>>>(
        h1b, W2T, (__hip_bfloat16*)nullptr, nullptr, nullptr, xl28, xr2b, N, 320, 256, 0);
    // ---- gat2 FUSED: h2 in-register -> z8 + xl3/xr3 (skip_add + gemm_vec1) ----
    gat_f8_kernel<100, 2, 112, 128, 100, 9, float, true>
        <<<N, 64, 0, stream>>>(xl28, xr2b, att2, b2, ioff, ssrc, (float*)nullptr,
                               wpre, z8, xl3, xr3, Wl3, Wr3, N);

    // ---- reconstruction loss ----
    loss_kernel<<<LOSS_BLOCKS, 256, 0, stream>>>(z8, ei, nei, part, LOSS_BLOCKS, E);

    // ---- layer 3 + finalize (last block) ----
    gat3_kernel<<<(N + 3) / 4 + 1, 256, 0, stream>>>(
        xl3, xr3, att3, b3, ioff, ssrc, out, N, part, LOSS_BLOCKS, c1, c2, E);
}

// Round 18
// 326.664 us; speedup vs baseline: 1.1418x; 1.0174x over previous
//
#include <hip/hip_runtime.h>
#include <hip/hip_bf16.h>

#define NODES 13627
#define DIM   500

typedef short short8 __attribute__((ext_vector_type(8)));
typedef float f32x4 __attribute__((ext_vector_type(4)));
typedef float floatx2 __attribute__((ext_vector_type(2)));

__device__ inline float wave_reduce_sum(float v) {
#pragma unroll
    for (int o = 32; o > 0; o >>= 1) v += __shfl_xor(v, o, 64);
    return v;
}

__device__ inline void store_v(float* p, float v) { *p = v; }
__device__ inline void store_v(__hip_bfloat16* p, float v) { *p = __float2bfloat16(v); }

// bf16 (packed pair in uint) -> f32, exact
__device__ inline float blo(unsigned w) { unsigned t = w << 16;        return __builtin_bit_cast(float, t); }
__device__ inline float bhi(unsigned w) { unsigned t = w & 0xffff0000u; return __builtin_bit_cast(float, t); }

// fp8 e4m3 (OCP, HW convert)
__device__ inline unsigned char to_fp8(float v) {
    int r = __builtin_amdgcn_cvt_pk_fp8_f32(v, v, 0, false);
    return (unsigned char)(r & 0xff);
}

// pack two floats into bf16x2 word (RNE)
__device__ inline unsigned pk2bf(float a, float b) {
    unsigned la = (unsigned)__builtin_bit_cast(unsigned short, __float2bfloat16(a));
    unsigned hb = (unsigned)__builtin_bit_cast(unsigned short, __float2bfloat16(b));
    return la | (hb << 16);
}

// ---- DPP 16-lane sum step: pure VALU (no ds_swizzle / lgkmcnt wait).
template <int CTRL>
__device__ inline float dpp_add_step(float v) {
    int s = __builtin_amdgcn_update_dpp(0, __builtin_bit_cast(int, v), CTRL, 0xf, 0xf, true);
    return v + __builtin_bit_cast(float, s);
}
__device__ inline float quad16_reduce(float v) {
    v = dpp_add_step<0x128>(v);   // row_ror:8
    v = dpp_add_step<0x124>(v);   // row_ror:4
    v = dpp_add_step<0x4E>(v);    // quad_perm [2,3,0,1]  (xor 2)
    v = dpp_add_step<0xB1>(v);    // quad_perm [1,0,3,2]  (xor 1)
    return v;
}

struct b4 { __hip_bfloat16 a, b, c, d; };

// ---------------------------------------------------------------------------
// CSR scan + scatter (hist fused into convert_all)
// ---------------------------------------------------------------------------
__global__ __launch_bounds__(1024) void scan_kernel(int* __restrict__ cnt_cur,
                                                    int* __restrict__ off, int n) {
    __shared__ int wsum[16];
    const int tid = threadIdx.x, lane = tid & 63, w = tid >> 6;
    int carry = 0;
    for (int base = 0; base < n; base += 1024) {
        int i = base + tid;
        int v = (i < n) ? cnt_cur[i] : 0;
        int s = v;
#pragma unroll
        for (int o = 1; o < 64; o <<= 1) {
            int t = __shfl_up(s, o, 64);
            if (lane >= o) s += t;
        }
        if (lane == 63) wsum[w] = s;
        __syncthreads();
        if (w == 0 && lane < 16) {
            int x = wsum[lane];
            int sx = x;
#pragma unroll
            for (int o = 1; o < 16; o <<= 1) {
                int t = __shfl_up(sx, o, 64);
                if (lane >= o) sx += t;
            }
            wsum[lane] = sx;
        }
        __syncthreads();
        int wo = (w == 0) ? 0 : wsum[w - 1];
        int total = wsum[15];
        int excl = carry + wo + (s - v);
        if (i < n) { off[i] = excl; cnt_cur[i] = excl; }
        carry += total;
        __syncthreads();
    }
    if (tid == 0) off[n] = carry;
}

__global__ __launch_bounds__(256) void scatter_kernel(const int* __restrict__ src,
                                                      const int* __restrict__ dst,
                                                      int* __restrict__ cur,
                                                      int* __restrict__ ssrc, int E) {
    int i = blockIdx.x * blockDim.x + threadIdx.x;
    if (i < E) {
        int p = atomicAdd(&cur[dst[i]], 1);
        ssrc[p] = src[i];
    }
}

// ---------------------------------------------------------------------------
// Fused conversion / packing + degree histogram.
// WcT = concat(W1T rows 0..639, WsT rows 0..255) for the fused GEMM.
// ---------------------------------------------------------------------------
__global__ __launch_bounds__(256) void convert_all_kernel(
    const float* __restrict__ x,
    const float* __restrict__ Wl1, const float* __restrict__ Wr1,
    const float* __restrict__ Wl2, const float* __restrict__ Wr2,
    const float* __restrict__ Ws1, const float* __restrict__ Ws2,
    const float* __restrict__ bs1, const float* __restrict__ bs2,
    __hip_bfloat16* __restrict__ WcT, __hip_bfloat16* __restrict__ W2T,
    float* __restrict__ bcat, __hip_bfloat16* __restrict__ xb,
    const int* __restrict__ dst, int* __restrict__ cnt, int E, int M) {
    int i = blockIdx.x * 256 + threadIdx.x;
    if (i < E) atomicAdd(&cnt[dst[i]], 1);   // fused degree histogram
    if (i < 327680) {
        int n = i >> 9, k = i & 511;
        float v = 0.f;
        if (k < 500) {
            if (n < 300) v = Wl1[k * 300 + n];
            else if (n < 600) v = Wr1[k * 300 + n - 300];
        }
        WcT[i] = __float2bfloat16(v);        // rows 0..639
    } else if (i < 409600) {
        int j = i - 327680;
        int n = j / 320, k = j - n * 320;
        float v = 0.f;
        if (k < 300) {
            if (n < 100) v = Wl2[k * 100 + n];
            else if (n < 200) v = Wr2[k * 100 + n - 100];
        }
        W2T[j] = __float2bfloat16(v);
    } else if (i < 540672) {
        int j = i - 409600;                  // [0, 131072) = 256x512
        int n = j >> 9, k = j & 511;
        float v = 0.f;
        if (k < 500) {
            if (n < 100) v = Ws1[k * 100 + n];
            else if (n < 200) v = Ws2[k * 100 + n - 100];
        }
        WcT[327680 + j] = __float2bfloat16(v);   // rows 640..895
    } else if (i < 540928) {
        int n = i - 540672;
        float v = 0.f;
        if (n < 100) v = bs1[n];
        else if (n < 200) v = bs2[n - 100];
        bcat[n] = v;
    } else {
        int j = i - 540928;
        if (j >= M * 128) return;
        int m = j >> 7, k = (j & 127) << 2;
        b4 o;
        if (k < 500) {
            float4 v = *(const float4*)(x + (size_t)m * 500 + k);
            o.a = __float2bfloat16(v.x); o.b = __float2bfloat16(v.y);
            o.c = __float2bfloat16(v.z); o.d = __float2bfloat16(v.w);
        } else {
            o.a = o.b = o.c = o.d = __float2bfloat16(0.f);
        }
        *(b4*)(xb + (size_t)m * 512 + k) = o;
    }
}

// ---------------------------------------------------------------------------
// bf16 MFMA GEMM: C[M,Nn] = A[M,Kp] @ BT[Nn,Kp]^T   (BM=128, BN=64, BK=32)
// R30: PERSISTENT grid-stride over tiles. R17 counters: traffic is already
// minimal (37MB = logical bytes) but at 780GB/s effective — the 1498-block
// grid ran as 1 full round + a 218-block tail round with ~85% of CUs idle.
// G=ceil(NT/2) blocks, each exactly 2 tiles -> zero tail, one round.
// R15 BK=32 loop layout (best total; R16 swizzle/prefetch + R17 BK=64 both
// regressed). XCD-chunk swizzle per logical tile (FETCH 58->12MB verified).
// ---------------------------------------------------------------------------
template <int EPI, typename TC>
__global__ __launch_bounds__(256) void mfma_gemm(
    const __hip_bfloat16* __restrict__ A, const __hip_bfloat16* __restrict__ BT,
    TC* __restrict__ C, const float* __restrict__ bias, const float* __restrict__ h2,
    unsigned char* __restrict__ p8, __hip_bfloat16* __restrict__ pb,
    int M, int Kp, int Nn, int NX, int NT) {
    __shared__ short AsF[8 * 64 * 8];
    __shared__ short BsF[4 * 64 * 8];
    const int t = threadIdx.x;
    const int w = t >> 6, lane = t & 63;
    const int c = t & 3, rr = t >> 2;
    const int q = lane >> 4, sl = lane & 15;

    for (int tid0 = blockIdx.x; tid0 < NT; tid0 += gridDim.x) {
        // ---- XCD-chunk swizzle (bijective, m204 formula) over logical tiles ----
        int id = tid0;
        {
            const int xcd = id & 7, idx = id >> 3;
            const int qq = NT >> 3, r8 = NT & 7;
            id = (xcd < r8 ? xcd * (qq + 1) : r8 * (qq + 1) + (xcd - r8) * qq) + idx;
        }
        const int m0 = (id / NX) * 128, n0 = (id % NX) * 64;

        f32x4 acc[2][4];
#pragma unroll
        for (int i = 0; i < 2; i++)
#pragma unroll
            for (int j = 0; j < 4; j++) acc[i][j] = (f32x4){0.f, 0.f, 0.f, 0.f};

        for (int k0 = 0; k0 < Kp; k0 += 32) {
#pragma unroll
            for (int r = 0; r < 2; r++) {
                int m = r * 64 + rr;
                int gm = m0 + m; if (gm >= M) gm = M - 1;
                float4 v = *(const float4*)(A + (size_t)gm * Kp + k0 + c * 8);
                int mi = m >> 4, slm = m & 15;
                *(float4*)(&AsF[(mi * 64 + c * 16 + slm) * 8]) = v;
            }
            {
                int n = rr;
                float4 v = *(const float4*)(BT + (size_t)(n0 + n) * Kp + k0 + c * 8);
                int ni = n >> 4, sln = n & 15;
                *(float4*)(&BsF[(ni * 64 + c * 16 + sln) * 8]) = v;
            }
            __syncthreads();
            short8 a0 = *(const short8*)(&AsF[((w * 2 + 0) * 64 + lane) * 8]);
            short8 a1 = *(const short8*)(&AsF[((w * 2 + 1) * 64 + lane) * 8]);
#pragma unroll
            for (int j = 0; j < 4; j++) {
                short8 b = *(const short8*)(&BsF[(j * 64 + lane) * 8]);
                acc[0][j] = __builtin_amdgcn_mfma_f32_16x16x32_bf16(a0, b, acc[0][j], 0, 0, 0);
                acc[1][j] = __builtin_amdgcn_mfma_f32_16x16x32_bf16(a1, b, acc[1][j], 0, 0, 0);
            }
            __syncthreads();
        }

#pragma unroll
        for (int i = 0; i < 2; i++) {
#pragma unroll
            for (int j = 0; j < 4; j++) {
#pragma unroll
                for (int reg = 0; reg < 4; reg++) {
                    int gm = m0 + w * 32 + i * 16 + q * 4 + reg;
                    int gn = n0 + j * 16 + sl;
                    if (gm >= M) continue;
                    float v = acc[i][j][reg];
                    if constexpr (EPI == 1) {
                        if (gn < 300)       p8[(size_t)gm * 304 + gn] = to_fp8(v);
                        else if (gn < 600)  pb[(size_t)gm * 320 + (gn - 300)] = __float2bfloat16(v);
                        else if (gn < 620)  pb[(size_t)gm * 320 + (gn - 300)] = __float2bfloat16(0.f);
                        else if (gn < 624)  p8[(size_t)gm * 304 + (gn - 320)] = 0;
                        else if (gn >= 640 && gn < 840) {
                            int cn = gn - 640;
                            ((float*)C)[(size_t)gm * 200 + cn] = fmaxf(v + bias[cn], 0.f);
                        }
                    } else if constexpr (EPI == 2) {
                        if (gn < 100)       p8[(size_t)gm * 112 + gn] = to_fp8(v);
                        else if (gn < 200)  pb[(size_t)gm * 128 + (gn - 100)] = __float2bfloat16(v);
                        else if (gn < 212)  p8[(size_t)gm * 112 + (gn - 100)] = 0;
                        else if (gn < 240)  pb[(size_t)gm * 128 + (gn - 112)] = __float2bfloat16(0.f);
                    } else {
                        store_v(&C[(size_t)gm * Nn + gn], v);
                    }
                }
            }
        }
    }
}

// ---------------------------------------------------------------------------
// GATv2 edge+aggregate on fp8 xl table (L2-resident) + bf16 xr.
// R22 structure. FUSE=true (gat2) folds skip_add + gemm_vec1 into epilogue.
// ---------------------------------------------------------------------------
template <int F, int NJ, int SL8, int SRB, int SOUT, int JSL, typename TOUT, bool FUSE>
__global__ __launch_bounds__(64, 4) void gat_f8_kernel(
    const unsigned char* __restrict__ xl8, const __hip_bfloat16* __restrict__ xrb,
    const float* __restrict__ att, const float* __restrict__ bias,
    const int* __restrict__ off, const int* __restrict__ ssrc,
    TOUT* __restrict__ out,
    const float* __restrict__ wpre, unsigned char* __restrict__ z8o,
    float* __restrict__ xl3, float* __restrict__ xr3,
    const float* __restrict__ wl3, const float* __restrict__ wr3, int n) {
    const int lane = threadIdx.x;
    const int sl = lane & 15, q = lane >> 4;
    const int wid = blockIdx.x;          // grid.x == n exactly

    floatx2 attv[NJ * 2], xrv[NJ * 2], acc[NJ * 2];
    const unsigned* xru = (const unsigned*)xrb + (size_t)wid * (SRB / 2);
#pragma unroll
    for (int j = 0; j < NJ; j++) {
        const int f0 = sl * 4 + j * 64;
        if (f0 < F) {
            float4 a4 = *(const float4*)(att + f0);
            attv[j * 2 + 0] = (floatx2){a4.x, a4.y};
            attv[j * 2 + 1] = (floatx2){a4.z, a4.w};
        } else {
            attv[j * 2 + 0] = (floatx2){0.f, 0.f};
            attv[j * 2 + 1] = (floatx2){0.f, 0.f};
        }
        unsigned u0 = __builtin_nontemporal_load(xru + (f0 >> 1));
        unsigned u1 = __builtin_nontemporal_load(xru + (f0 >> 1) + 1);
        xrv[j * 2 + 0] = (floatx2){blo(u0), bhi(u0)};
        xrv[j * 2 + 1] = (floatx2){blo(u1), bhi(u1)};
        acc[j * 2 + 0] = (floatx2){0.f, 0.f};
        acc[j * 2 + 1] = (floatx2){0.f, 0.f};
    }

    const int s0 = off[wid], s1 = off[wid + 1];
    const int eb = s0 - 1;              // self loop lives at slot s0-1
    const int ee = s1;
    float den = 0.f;
    const int myoff = sl * 4;

    // ---- pipeline prologue: indices for iter 0 and 1, rows for iter 0 ----
    int srcB;
    unsigned u[NJ];
    {
        int eq0 = eb + q;
        int srcA = wid;
        if (eq0 >= s0 && eq0 < ee) srcA = __builtin_nontemporal_load(ssrc + eq0);
        int eq1 = eb + 4 + q;
        srcB = wid;
        if (eq1 >= s0 && eq1 < ee) srcB = __builtin_nontemporal_load(ssrc + eq1);
        const unsigned char* row = xl8 + (size_t)srcA * SL8;
#pragma unroll
        for (int j = 0; j < NJ; j++) {
            const bool ld = (j < NJ - 1) || (sl < JSL);
            u[j] = ld ? *(const unsigned*)(row + myoff + j * 64) : 0u;
        }
    }

    // ---- deferred-softmax pending state (nothing pending yet: gate = 0) ----
    float p_pend = 0.f, gate = 0.f;
    unsigned u_pend[NJ];
#pragma unroll
    for (int j = 0; j < NJ; j++) u_pend[j] = 0u;

    for (int e0 = eb; e0 < ee; e0 += 4) {
        // ---- issue index load for iteration i+2 ----
        int srcC = wid;
        {
            int eq2 = e0 + 8 + q;
            if (eq2 >= s0 && eq2 < ee) srcC = __builtin_nontemporal_load(ssrc + eq2);
        }
        // ---- issue row loads for iteration i+1 (index already resident) ----
        unsigned un[NJ];
        {
            const unsigned char* row1 = xl8 + (size_t)srcB * SL8;
#pragma unroll
            for (int j = 0; j < NJ; j++) {
                const bool ld = (j < NJ - 1) || (sl < JSL);
                un[j] = ld ? *(const unsigned*)(row1 + myoff + j * 64) : 0u;
            }
        }
        // ---- finish PENDING quad: DPP reduce -> exp -> re-decode -> acc ----
        {
            float pp = quad16_reduce(p_pend);
            float ex = gate * __expf(pp);
            den += ex;
            floatx2 ex2 = (floatx2){ex, ex};
#pragma unroll
            for (int j = 0; j < NJ; j++) {
                floatx2 lo = __builtin_amdgcn_cvt_pk_f32_fp8((int)u_pend[j], false);
                floatx2 hi = __builtin_amdgcn_cvt_pk_f32_fp8((int)u_pend[j], true);
                acc[j * 2 + 0] += ex2 * lo;
                acc[j * 2 + 1] += ex2 * hi;
            }
        }
        // ---- CURRENT quad score (packed f32x2) -> becomes pending ----
        {
            floatx2 p2 = (floatx2){0.f, 0.f};
#pragma unroll
            for (int j = 0; j < NJ; j++) {
                floatx2 lo = __builtin_amdgcn_cvt_pk_f32_fp8((int)u[j], false);
                floatx2 hi = __builtin_amdgcn_cvt_pk_f32_fp8((int)u[j], true);
                floatx2 s0v = lo + xrv[j * 2 + 0];
                floatx2 s1v = hi + xrv[j * 2 + 1];
                floatx2 g0 = __builtin_elementwise_max(s0v, 0.2f * s0v);
                floatx2 g1 = __builtin_elementwise_max(s1v, 0.2f * s1v);
                p2 += attv[j * 2 + 0] * g0;
                p2 += attv[j * 2 + 1] * g1;
            }
            p_pend = p2.x + p2.y;
            gate = ((e0 + q) < ee) ? 1.f : 0.f;
        }
        // ---- rotate pipeline (u -> u_pend, un -> u) ----
#pragma unroll
        for (int j = 0; j < NJ; j++) { u_pend[j] = u[j]; u[j] = un[j]; }
        srcB = srcC;
    }
    // ---- drain the final pending quad ----
    {
        float pp = quad16_reduce(p_pend);
        float ex = gate * __expf(pp);
        den += ex;
        floatx2 ex2 = (floatx2){ex, ex};
#pragma unroll
        for (int j = 0; j < NJ; j++) {
            floatx2 lo = __builtin_amdgcn_cvt_pk_f32_fp8((int)u_pend[j], false);
            floatx2 hi = __builtin_amdgcn_cvt_pk_f32_fp8((int)u_pend[j], true);
            acc[j * 2 + 0] += ex2 * lo;
            acc[j * 2 + 1] += ex2 * hi;
        }
    }

    // cross-quad butterfly (crosses 16-lane rows, DPP can't — keep shfl)
    float* af = (float*)acc;
#pragma unroll
    for (int o = 16; o <= 32; o <<= 1) {
        den += __shfl_xor(den, o, 64);
#pragma unroll
        for (int i = 0; i < NJ * 4; i++) af[i] += __shfl_xor(af[i], o, 64);
    }

    if (q == 0) {
        const float inv = 1.f / (den + 1e-16f);
        if constexpr (FUSE) {
            // fused: h2 in-register -> z8 + layer-3 projections (row-local)
            float pl = 0.f, pr = 0.f;
#pragma unroll
            for (int j = 0; j < NJ; j++) {
                const int f0 = sl * 4 + j * 64;
#pragma unroll
                for (int cc = 0; cc < 4; cc++) {
                    const int f = f0 + cc;
                    if (f < F) {
                        float h2v = fmaxf(af[j * 4 + cc] * inv + bias[f], 0.f);
                        float preA = wpre[(size_t)wid * 200 + f];
                        float preB = wpre[(size_t)wid * 200 + 100 + f];
                        float xov = preA + h2v;
                        z8o[(size_t)wid * 128 + f] = to_fp8(preB + h2v);
                        pl += xov * wl3[f];
                        pr += xov * wr3[f];
                    } else {
                        z8o[(size_t)wid * 128 + f] = 0;
                    }
                }
            }
            pl = quad16_reduce(pl);
            pr = quad16_reduce(pr);
            if (sl == 0) { xl3[wid] = pl; xr3[wid] = pr; }
        } else {
#pragma unroll
            for (int j = 0; j < NJ; j++) {
                const int f0 = sl * 4 + j * 64;
                if (f0 >= SOUT) continue;
                float r[4];
#pragma unroll
                for (int cc = 0; cc < 4; cc++) {
                    const int f = f0 + cc;
                    float v = 0.f;
                    if (f < F) v = fmaxf(af[j * 4 + cc] * inv + bias[f], 0.f);
                    r[cc] = v;
                }
                if constexpr (sizeof(TOUT) == 4) {   // float out
                    *(float4*)((float*)out + (size_t)wid * SOUT + f0) =
                        make_float4(r[0], r[1], r[2], r[3]);
                } else {                             // bf16 out
                    unsigned* op = (unsigned*)out + (size_t)wid * (SOUT / 2) + (f0 >> 1);
                    op[0] = pk2bf(r[0], r[1]);
                    op[1] = pk2bf(r[2], r[3]);
                }
            }
        }
    }
}

// ---------------------------------------------------------------------------
// Layer-3 GAT (F=1): wave per node + finalize folded into the LAST block.
// ---------------------------------------------------------------------------
__global__ __launch_bounds__(256) void gat3_kernel(
    const float* __restrict__ xl3, const float* __restrict__ xr3,
    const float* __restrict__ att3, const float* __restrict__ b3,
    const int* __restrict__ off, const int* __restrict__ ssrc,
    float* __restrict__ out, int n,
    const float* __restrict__ part, int nb,
    const float* __restrict__ c1, const float* __restrict__ c2, int E) {
    __shared__ float sp[4], sn[4];
    if (blockIdx.x == gridDim.x - 1) {
        const int tid = threadIdx.x, lane = tid & 63, w = tid >> 6;
        float p = 0.f, q2 = 0.f;
        for (int i = tid; i < nb; i += 256) { p += part[i]; q2 += part[nb + i]; }
        p = wave_reduce_sum(p);
        q2 = wave_reduce_sum(q2);
        if (lane == 0) { sp[w] = p; sn[w] = q2; }
        __syncthreads();
        if (tid == 0) {
            float tp = sp[0] + sp[1] + sp[2] + sp[3];
            float tq = sn[0] + sn[1] + sn[2] + sn[3];
            out[n]     = -(tp + tq) / (float)E;
            out[n + 1] = c1[0];
            out[n + 2] = c2[0];
        }
        return;
    }
    const int wid = blockIdx.x * 4 + (threadIdx.x >> 6);
    const int lane = threadIdx.x & 63;
    if (wid >= n) return;
    const float xrv = xr3[wid];
    const float att = att3[0];
    float num = 0.f, den = 0.f;
    const int s0 = off[wid], s1 = off[wid + 1];
    for (int e = s0 - 1 + lane; e < s1; e += 64) {
        int src = (e < s0) ? wid : ssrc[e];
        float xlv = xl3[src];
        float t = xlv + xrv;
        float g = t > 0.f ? t : 0.2f * t;
        float ex = __expf(g * att);
        den += ex;
        num += ex * xlv;
    }
    num = wave_reduce_sum(num);
    den = wave_reduce_sum(den);
    if (lane == 0) out[wid] = num / (den + 1e-16f) + b3[0];
}

// ---------------------------------------------------------------------------
// Link-prediction loss on fp8 z [N,128]. 16-lane/edge coalesced + DPP reduce.
// ---------------------------------------------------------------------------
__global__ __launch_bounds__(256) void loss_kernel(
    const unsigned char* __restrict__ z8, const int* __restrict__ pos,
    const int* __restrict__ neg, float* __restrict__ part, int nb, int E) {
    const int lane = threadIdx.x & 63;
    const int sl = lane & 15;
    const int wlocal = threadIdx.x >> 6;
    const int q = lane >> 4;
    const int nq = gridDim.x * 16;
    const int qid = (blockIdx.x * 4 + wlocal) * 4 + q;
    const int total = 2 * E;
    float psum = 0.f, nsum = 0.f;

    for (int base = qid; base < total; base += 4 * nq) {
        uint2 au[4], bu[4];
        bool act[4], isN[4];
#pragma unroll
        for (int s = 0; s < 4; s++) {
            int it = base + s * nq;
            act[s] = it < total;
            int itc = act[s] ? it : 0;
            isN[s] = itc >= E;
            int e = isN[s] ? itc - E : itc;
            const int* ei = isN[s] ? neg : pos;
            int u = ei[e], v = ei[E + e];
            au[s] = *(const uint2*)(z8 + (size_t)u * 128 + sl * 8);
            bu[s] = *(const uint2*)(z8 + (size_t)v * 128 + sl * 8);
        }
#pragma unroll
        for (int s = 0; s < 4; s++) {
            floatx2 a0 = __builtin_amdgcn_cvt_pk_f32_fp8((int)au[s].x, false);
            floatx2 a1 = __builtin_amdgcn_cvt_pk_f32_fp8((int)au[s].x, true);
            floatx2 a2 = __builtin_amdgcn_cvt_pk_f32_fp8((int)au[s].y, false);
            floatx2 a3 = __builtin_amdgcn_cvt_pk_f32_fp8((int)au[s].y, true);
            floatx2 b0 = __builtin_amdgcn_cvt_pk_f32_fp8((int)bu[s].x, false);
            floatx2 b1 = __builtin_amdgcn_cvt_pk_f32_fp8((int)bu[s].x, true);
            floatx2 b2 = __builtin_amdgcn_cvt_pk_f32_fp8((int)bu[s].y, false);
            floatx2 b3 = __builtin_amdgcn_cvt_pk_f32_fp8((int)bu[s].y, true);
            float p = a0.x * b0.x + a0.y * b0.y + a1.x * b1.x + a1.y * b1.y
                    + a2.x * b2.x + a2.y * b2.y + a3.x * b3.x + a3.y * b3.y;
            p = quad16_reduce(p);
            if (sl == 0 && act[s]) {
                float sig = __builtin_amdgcn_rcpf(1.f + __expf(-p));
                if (isN[s]) nsum += __logf(1.f - sig + 1e-15f);
                else        psum += __logf(sig + 1e-15f);
            }
        }
    }
    float pw = wave_reduce_sum(psum);
    float nw = wave_reduce_sum(nsum);
    __shared__ float sp[4], sn[4];
    if (lane == 0) { sp[wlocal] = pw; sn[wlocal] = nw; }
    __syncthreads();
    if (threadIdx.x == 0) {
        part[blockIdx.x]      = sp[0] + sp[1] + sp[2] + sp[3];
        part[nb + blockIdx.x] = sn[0] + sn[1] + sn[2] + sn[3];
    }
}

// ---------------------------------------------------------------------------
extern "C" void kernel_launch(void* const* d_in, const int* in_sizes, int n_in,
                              void* d_out, int out_size, void* d_ws, size_t ws_size,
                              hipStream_t stream) {
    const float* x      = (const float*)d_in[0];
    const int*   ei     = (const int*)d_in[1];
    const int*   nei    = (const int*)d_in[2];
    const float* Wl1    = (const float*)d_in[3];
    const float* Wr1    = (const float*)d_in[4];
    const float* att1   = (const float*)d_in[5];
    const float* b1     = (const float*)d_in[6];
    const float* Wl2    = (const float*)d_in[7];
    const float* Wr2    = (const float*)d_in[8];
    const float* att2   = (const float*)d_in[9];
    const float* b2     = (const float*)d_in[10];
    const float* Wl3    = (const float*)d_in[11];
    const float* Wr3    = (const float*)d_in[12];
    const float* att3   = (const float*)d_in[13];
    const float* b3     = (const float*)d_in[14];
    const float* Wlin1  = (const float*)d_in[15];
    const float* blin1  = (const float*)d_in[16];
    const float* Wlin2  = (const float*)d_in[17];
    const float* blin2  = (const float*)d_in[18];
    const float* c1     = (const float*)d_in[19];
    const float* c2     = (const float*)d_in[20];
    float* out = (float*)d_out;

    const int E = in_sizes[1] / 2;   // 504378
    const int N = NODES;
    const int LOSS_BLOCKS = 4096;

    // ---- workspace carve (bytes); ws_size = 256MB, we use ~50MB ----
    char* ws = (char*)d_ws;
    unsigned char*  xl8  = (unsigned char*)(ws + 0);          // [N,304] fp8
    unsigned char*  xl28 = (unsigned char*)(ws + 0);          // [N,112] fp8 (after gat1)
    __hip_bfloat16* xrb  = (__hip_bfloat16*)(ws + 4194304);   // [N,320] bf16
    __hip_bfloat16* xr2b = (__hip_bfloat16*)(ws + 4194304);   // [N,128] bf16 (after gat1)
    unsigned char*  z8   = (unsigned char*)(ws + 9645312);    // [N,128] fp8
    __hip_bfloat16* h1b  = (__hip_bfloat16*)(ws + 12915712);  // [N,320] bf16 (gat1 -> L2 GEMM)
    __hip_bfloat16* xb   = (__hip_bfloat16*)(ws + 21637120);  // [N,512] bf16
    __hip_bfloat16* WcT  = (__hip_bfloat16*)(ws + 35591168);  // [896,512] (W1|Ws)
    __hip_bfloat16* W2T  = (__hip_bfloat16*)(ws + 36508672);  // [256,320]
    float*          bcat = (float*)(ws + 36672512);           // [256]
    float*          xl3  = (float*)(ws + 36673536);
    float*          xr3  = (float*)(ws + 36728064);
    int*            ioff = (int*)(ws + 36782592);             // N+1
    int*            cur  = (int*)(ws + 36837376);             // N
    int*            ssrc = (int*)(ws + 36892160);             // E
    float*          part = (float*)(ws + 38909952);           // [2*LOSS_BLOCKS]
    float*          wpre = (float*)(ws + 39000064);           // [N,200] f32 skip-pre

    hipMemsetAsync(cur, 0, sizeof(int) * N, stream);

    // ---- pack inputs/weights + degree histogram (one fused launch) ----
    convert_all_kernel<<<(540928 + N * 128 + 255) / 256, 256, 0, stream>>>(
        x, Wl1, Wr1, Wl2, Wr2, Wlin1, Wlin2, blin1, blin2,
        WcT, W2T, bcat, xb, ei + E, cur, E, N);

    // ---- CSR: scan + scatter ----
    scan_kernel<<<1, 1024, 0, stream>>>(cur, ioff, N);
    scatter_kernel<<<(E + 255) / 256, 256, 0, stream>>>(ei, ei + E, cur, ssrc, E);

    // ---- layer 1 GEMM fused with skip GEMM: persistent (2 tiles/block) ----
    {
        const int NX = 14, NT = NX * 107;          // 1498 tiles
        const int G = (NT + 1) / 2;                // 749 blocks, 2 tiles each
        mfma_gemm<1, float><<<G, 256, 0, stream>>>(
            xb, WcT, wpre, bcat, nullptr, xl8, xrb, N, 512, 896, NX, NT);
    }
    gat_f8_kernel<300, 5, 304, 320, 320, 11, __hip_bfloat16, false>
        <<<N, 64, 0, stream>>>(xl8, xrb, att1, b1, ioff, ssrc, h1b,
                               nullptr, nullptr, nullptr, nullptr, nullptr, nullptr, N);

    // ---- layer 2: GEMM -> xl28 fp8 [N,112] + xr2b bf16 [N,128] ----
    {
        const int NX = 4, NT = NX * 107;           // 428 tiles, under capacity
        mfma_gemm<2, __hip_bfloat16><<<NT, 256, 0, stream>>>(
            h1b, W2T, (__hip_bfloat16*)nullptr, nullptr, nullptr, xl28, xr2b,
            N, 320, 256, NX, NT);
    }
    // ---- gat2 FUSED: h2 in-register -> z8 + xl3/xr3 (skip_add + gemm_vec1) ----
    gat_f8_kernel<100, 2, 112, 128, 100, 9, float, true>
        <<<N, 64, 0, stream>>>(xl28, xr2b, att2, b2, ioff, ssrc, (float*)nullptr,
                               wpre, z8, xl3, xr3, Wl3, Wr3, N);

    // ---- reconstruction loss ----
    loss_kernel<<<LOSS_BLOCKS, 256, 0, stream>>>(z8, ei, nei, part, LOSS_BLOCKS, E);

    // ---- layer 3 + finalize (last block) ----
    gat3_kernel<<<(N + 3) / 4 + 1, 256, 0, stream>>>(
        xl3, xr3, att3, b3, ioff, ssrc, out, N, part, LOSS_BLOCKS, c1, c2, E);
}